// Round 2
// baseline (120.834 us; speedup 1.0000x reference)
//
#include <hip/hip_runtime.h>

// KernelExpansion: out[m] = sum_n sigma^2 * w[n] * exp(-0.5*||s_n - x_m||^2 / l^2)
// N=8192 samples, M=16384 x-rows, D=24, all fp32. Compute-bound (inputs ~2.4MB,
// L2-resident). Strategy: fp32 VALU kernel, 2 m-rows per thread (x in regs),
// wave-uniform scalar reads of samples rows, exp folded to exp2 with
// c = -0.5*log2e/l^2. Per-n constants (c*||s_n||^2, sigma^2*w_n) precomputed
// into d_ws. n split 64-way; fp32 atomicAdd into zeroed d_out.

#define LOG2E_F 1.4426950408889634f

constexpr int D    = 24;
constexpr int TPB  = 256;  // threads per block
constexpr int MPT  = 2;    // m-rows per thread
constexpr int MBLK = TPB * MPT;  // 512 m per block

__global__ void ke_setup(const float* __restrict__ samples,
                         const float* __restrict__ weights,
                         const float* __restrict__ sigma_p,
                         const float* __restrict__ length_p,
                         float2* __restrict__ csw, int N) {
    int n = blockIdx.x * blockDim.x + threadIdx.x;
    if (n >= N) return;
    float l  = length_p[0];
    float sg = sigma_p[0];
    float c  = -0.5f * LOG2E_F / (l * l);
    const float* s = samples + n * D;
    float ssq = 0.f;
#pragma unroll
    for (int d = 0; d < D; ++d) ssq = fmaf(s[d], s[d], ssq);
    csw[n] = make_float2(c * ssq, sg * sg * weights[n]);
}

template <bool HAVE_CSW>
__global__ __launch_bounds__(TPB) void ke_main(
    const float* __restrict__ x,
    const float* __restrict__ samples,
    const float2* __restrict__ csw,
    const float* __restrict__ weights,
    const float* __restrict__ sigma_p,
    const float* __restrict__ length_p,
    float* __restrict__ out,
    int M, int N, int nsplit, int chunk) {
    int mb = blockIdx.x / nsplit;
    int ns = blockIdx.x - mb * nsplit;
    int t  = threadIdx.x;
    int m0 = mb * MBLK + t;
    int m1 = m0 + TPB;
    int m0c = (m0 < M) ? m0 : 0;
    int m1c = (m1 < M) ? m1 : 0;

    // Load this thread's two x rows into registers (6x float4 each, 16B-aligned
    // since row stride = 96B).
    float xa[D], xb[D];
    const float4* xp0 = reinterpret_cast<const float4*>(x + m0c * D);
    const float4* xp1 = reinterpret_cast<const float4*>(x + m1c * D);
#pragma unroll
    for (int q = 0; q < D / 4; ++q) {
        float4 va = xp0[q];
        float4 vb = xp1[q];
        xa[4 * q + 0] = va.x; xa[4 * q + 1] = va.y;
        xa[4 * q + 2] = va.z; xa[4 * q + 3] = va.w;
        xb[4 * q + 0] = vb.x; xb[4 * q + 1] = vb.y;
        xb[4 * q + 2] = vb.z; xb[4 * q + 3] = vb.w;
    }

    float l   = length_p[0];
    float c   = -0.5f * LOG2E_F / (l * l);
    float m2c = -2.f * c;
    float sg2 = 0.f;
    if (!HAVE_CSW) {
        float sg = sigma_p[0];
        sg2 = sg * sg;
    }

    float cxa = 0.f, cxb = 0.f;
#pragma unroll
    for (int d = 0; d < D; ++d) {
        cxa = fmaf(xa[d], xa[d], cxa);
        cxb = fmaf(xb[d], xb[d], cxb);
    }
    cxa *= c;
    cxb *= c;

    float acc0 = 0.f, acc1 = 0.f;
    int n0 = ns * chunk;
    int n1 = n0 + chunk;
    if (n1 > N) n1 = N;

    for (int n = n0; n < n1; ++n) {
        const float* s = samples + n * D;  // wave-uniform address -> s_load
        float cn, wn;
        float dot0 = 0.f, dot1 = 0.f;
        if (HAVE_CSW) {
            float2 cw = csw[n];
            cn = cw.x;
            wn = cw.y;
#pragma unroll
            for (int d = 0; d < D; ++d) {
                float sv = s[d];
                dot0 = fmaf(sv, xa[d], dot0);
                dot1 = fmaf(sv, xb[d], dot1);
            }
        } else {
            float ssq = 0.f;
#pragma unroll
            for (int d = 0; d < D; ++d) {
                float sv = s[d];
                ssq  = fmaf(sv, sv, ssq);
                dot0 = fmaf(sv, xa[d], dot0);
                dot1 = fmaf(sv, xb[d], dot1);
            }
            cn = c * ssq;
            wn = sg2 * weights[n];
        }
        float a0 = fmaf(m2c, dot0, cn + cxa);
        float a1 = fmaf(m2c, dot1, cn + cxb);
        acc0 = fmaf(wn, __builtin_amdgcn_exp2f(a0), acc0);
        acc1 = fmaf(wn, __builtin_amdgcn_exp2f(a1), acc1);
    }

    if (m0 < M) atomicAdd(&out[m0], acc0);
    if (m1 < M) atomicAdd(&out[m1], acc1);
}

extern "C" void kernel_launch(void* const* d_in, const int* in_sizes, int n_in,
                              void* d_out, int out_size, void* d_ws, size_t ws_size,
                              hipStream_t stream) {
    const float* x       = (const float*)d_in[0];
    const float* samples = (const float*)d_in[1];
    const float* weights = (const float*)d_in[2];
    const float* sigma_p = (const float*)d_in[3];
    const float* length_p= (const float*)d_in[4];
    float* out = (float*)d_out;

    int M = in_sizes[0] / D;
    int N = in_sizes[1] / D;

    hipMemsetAsync(out, 0, (size_t)out_size * sizeof(float), stream);

    bool have_csw = ws_size >= (size_t)N * sizeof(float2);
    float2* csw = (float2*)d_ws;
    if (have_csw) {
        ke_setup<<<dim3((N + TPB - 1) / TPB), dim3(TPB), 0, stream>>>(
            samples, weights, sigma_p, length_p, csw, N);
    }

    int mbcnt  = (M + MBLK - 1) / MBLK;            // 32 for M=16384
    int nsplit = 2048 / mbcnt;                     // target ~2048 blocks
    if (nsplit < 1) nsplit = 1;
    if (nsplit > N) nsplit = N;
    int chunk = (N + nsplit - 1) / nsplit;         // 128 for N=8192

    dim3 grid(mbcnt * nsplit);
    dim3 block(TPB);
    if (have_csw) {
        ke_main<true><<<grid, block, 0, stream>>>(
            x, samples, csw, weights, sigma_p, length_p, out, M, N, nsplit, chunk);
    } else {
        ke_main<false><<<grid, block, 0, stream>>>(
            x, samples, csw, weights, sigma_p, length_p, out, M, N, nsplit, chunk);
    }
}

// Round 3
// 79.710 us; speedup vs baseline: 1.5159x; 1.5159x over previous
//
#include <hip/hip_runtime.h>

// KernelExpansion: out[m] = sum_n sigma^2 * w[n] * exp(-0.5*||s_n - x_m||^2 / l^2)
// N=8192, M=16384, D=24, fp32. Compute-bound (VALU). Round-3 changes:
//  - asm-pin x rows into VGPRs (round-2 showed VGPR=32 -> compiler sank x loads
//    into the n-loop, re-reading from L1 every iteration: the 2x overhead)
//  - packed fp32 dots via v_pk_fma_f32 (ext_vector float2 + elementwise_fma)
//  - exp2(c*||x||^2) factored out of the n-loop, applied once at the end
// Per-n constants (c*||s_n||^2, sigma^2*w_n) precomputed into d_ws.
// n split 64-way; fp32 atomicAdd into zeroed d_out.

#define LOG2E_F 1.4426950408889634f

typedef float v2f __attribute__((ext_vector_type(2)));

constexpr int D    = 24;
constexpr int DQ   = D / 2;      // 12 float2 per row
constexpr int TPB  = 256;        // threads per block
constexpr int MPT  = 2;          // m-rows per thread
constexpr int MBLK = TPB * MPT;  // 512 m per block

__global__ void ke_setup(const float* __restrict__ samples,
                         const float* __restrict__ weights,
                         const float* __restrict__ sigma_p,
                         const float* __restrict__ length_p,
                         float2* __restrict__ csw, int N) {
    int n = blockIdx.x * blockDim.x + threadIdx.x;
    if (n >= N) return;
    float l  = length_p[0];
    float sg = sigma_p[0];
    float c  = -0.5f * LOG2E_F / (l * l);
    const float* s = samples + (size_t)n * D;
    float ssq = 0.f;
#pragma unroll
    for (int d = 0; d < D; ++d) ssq = fmaf(s[d], s[d], ssq);
    csw[n] = make_float2(c * ssq, sg * sg * weights[n]);
}

template <bool HAVE_CSW>
__global__ __launch_bounds__(TPB) void ke_main(
    const float* __restrict__ x,
    const float* __restrict__ samples,
    const float2* __restrict__ csw,
    const float* __restrict__ weights,
    const float* __restrict__ sigma_p,
    const float* __restrict__ length_p,
    float* __restrict__ out,
    int M, int N, int nsplit, int chunk) {
    int mb = blockIdx.x / nsplit;
    int ns = blockIdx.x - mb * nsplit;
    int t  = threadIdx.x;
    int m0 = mb * MBLK + t;
    int m1 = m0 + TPB;
    int m0c = (m0 < M) ? m0 : 0;
    int m1c = (m1 < M) ? m1 : 0;

    // Load this thread's two x rows as 12 float2 pairs each (rows are 96B,
    // 8B-aligned always), then PIN them in VGPRs: round-2 profile showed the
    // compiler otherwise sinks these loads into the n-loop (VGPR_Count=32).
    v2f xaq[DQ], xbq[DQ];
    const v2f* xp0 = reinterpret_cast<const v2f*>(x + (size_t)m0c * D);
    const v2f* xp1 = reinterpret_cast<const v2f*>(x + (size_t)m1c * D);
#pragma unroll
    for (int q = 0; q < DQ; ++q) {
        xaq[q] = xp0[q];
        xbq[q] = xp1[q];
    }
#pragma unroll
    for (int q = 0; q < DQ; ++q) {
        asm("" : "+v"(xaq[q]));
        asm("" : "+v"(xbq[q]));
    }

    float l   = length_p[0];
    float c   = -0.5f * LOG2E_F / (l * l);
    float m2c = -2.f * c;
    float sg2 = 0.f;
    if (!HAVE_CSW) {
        float sg = sigma_p[0];
        sg2 = sg * sg;
    }

    // c * ||x||^2 for both rows (factored out of the n-loop as exp2(cx*)).
    v2f qa = {0.f, 0.f}, qb = {0.f, 0.f};
#pragma unroll
    for (int q = 0; q < DQ; ++q) {
        qa = __builtin_elementwise_fma(xaq[q], xaq[q], qa);
        qb = __builtin_elementwise_fma(xbq[q], xbq[q], qb);
    }
    float cxa = c * (qa.x + qa.y);
    float cxb = c * (qb.x + qb.y);

    float acc0 = 0.f, acc1 = 0.f;
    int n0 = ns * chunk;
    int n1 = n0 + chunk;
    if (n1 > N) n1 = N;

#pragma unroll 2
    for (int n = n0; n < n1; ++n) {
        // Wave-uniform row address -> scalar (constant-cache) loads.
        const v2f* s2 = reinterpret_cast<const v2f*>(samples + (size_t)n * D);
        float cn, wn;
        v2f da = {0.f, 0.f}, db = {0.f, 0.f};
        if (HAVE_CSW) {
            float2 cw = csw[n];
            cn = cw.x;
            wn = cw.y;
#pragma unroll
            for (int q = 0; q < DQ; ++q) {
                v2f sv = s2[q];
                da = __builtin_elementwise_fma(sv, xaq[q], da);
                db = __builtin_elementwise_fma(sv, xbq[q], db);
            }
        } else {
            v2f sq = {0.f, 0.f};
#pragma unroll
            for (int q = 0; q < DQ; ++q) {
                v2f sv = s2[q];
                sq = __builtin_elementwise_fma(sv, sv, sq);
                da = __builtin_elementwise_fma(sv, xaq[q], da);
                db = __builtin_elementwise_fma(sv, xbq[q], db);
            }
            cn = c * (sq.x + sq.y);
            wn = sg2 * weights[n];
        }
        float dot0 = da.x + da.y;
        float dot1 = db.x + db.y;
        float e0 = fmaf(m2c, dot0, cn);
        float e1 = fmaf(m2c, dot1, cn);
        acc0 = fmaf(wn, __builtin_amdgcn_exp2f(e0), acc0);
        acc1 = fmaf(wn, __builtin_amdgcn_exp2f(e1), acc1);
    }

    if (m0 < M) atomicAdd(&out[m0], acc0 * __builtin_amdgcn_exp2f(cxa));
    if (m1 < M) atomicAdd(&out[m1], acc1 * __builtin_amdgcn_exp2f(cxb));
}

extern "C" void kernel_launch(void* const* d_in, const int* in_sizes, int n_in,
                              void* d_out, int out_size, void* d_ws, size_t ws_size,
                              hipStream_t stream) {
    const float* x       = (const float*)d_in[0];
    const float* samples = (const float*)d_in[1];
    const float* weights = (const float*)d_in[2];
    const float* sigma_p = (const float*)d_in[3];
    const float* length_p= (const float*)d_in[4];
    float* out = (float*)d_out;

    int M = in_sizes[0] / D;
    int N = in_sizes[1] / D;

    hipMemsetAsync(out, 0, (size_t)out_size * sizeof(float), stream);

    bool have_csw = ws_size >= (size_t)N * sizeof(float2);
    float2* csw = (float2*)d_ws;
    if (have_csw) {
        ke_setup<<<dim3((N + TPB - 1) / TPB), dim3(TPB), 0, stream>>>(
            samples, weights, sigma_p, length_p, csw, N);
    }

    int mbcnt  = (M + MBLK - 1) / MBLK;            // 32 for M=16384
    int nsplit = 2048 / mbcnt;                     // target ~2048 blocks
    if (nsplit < 1) nsplit = 1;
    if (nsplit > N) nsplit = N;
    int chunk = (N + nsplit - 1) / nsplit;         // 128 for N=8192

    dim3 grid(mbcnt * nsplit);
    dim3 block(TPB);
    if (have_csw) {
        ke_main<true><<<grid, block, 0, stream>>>(
            x, samples, csw, weights, sigma_p, length_p, out, M, N, nsplit, chunk);
    } else {
        ke_main<false><<<grid, block, 0, stream>>>(
            x, samples, csw, weights, sigma_p, length_p, out, M, N, nsplit, chunk);
    }
}

// Round 4
// 57.916 us; speedup vs baseline: 2.0864x; 1.3763x over previous
//
#include <hip/hip_runtime.h>

// KernelExpansion: out[m] = sum_n sigma^2 * w[n] * exp(-0.5*||s_n - x_m||^2 / l^2)
// Round-4: MFMA formulation. dot(s_n, x_m) via bf16 hi/lo split (3 passes of
// mfma_f32_16x16x32_bf16, K=32 with D=24 zero-padded). Per-n factor
// w'_n = sigma^2 w_n 2^{c2 ||s||^2} folded in setup; per-m factor 2^{c2 ||x||^2}
// applied once at the end. Weighted n-reduction in-register per C-fragment
// (C/D: col=lane&15, row=(lane>>4)*4+reg), shfl_xor(16,32) final reduce.
// Fallback to fp32 VALU kernel if workspace too small / shapes don't divide.

#define LOG2E_F 1.4426950408889634f

typedef float v2f __attribute__((ext_vector_type(2)));
typedef __attribute__((ext_vector_type(8))) short bf16x8;   // 8 bf16 = 4 VGPRs
typedef __attribute__((ext_vector_type(4))) float f32x4;

constexpr int D      = 24;
constexpr int KP     = 32;   // padded K (cols 24..31 zero)
constexpr int NSPLIT = 16;   // n-chunks per column-group
constexpr int TPB    = 256;

__device__ inline unsigned short f32_to_bf16_rne(float f) {
    unsigned u = __builtin_bit_cast(unsigned, f);
    u += 0x7fffu + ((u >> 16) & 1u);
    return (unsigned short)(u >> 16);
}
__device__ inline float bf16_to_f32(unsigned short h) {
    unsigned u = ((unsigned)h) << 16;
    return __builtin_bit_cast(float, u);
}

// ---- setup: x -> (x_hi, x_lo bf16 [M][32]), cx[m] = c2*||x||^2 (log2 units)
__global__ void prep_x(const float* __restrict__ x, const float* __restrict__ length_p,
                       unsigned short* __restrict__ xhi, unsigned short* __restrict__ xlo,
                       float* __restrict__ cx, int M) {
    int m = blockIdx.x * blockDim.x + threadIdx.x;
    if (m >= M) return;
    float l  = length_p[0];
    float c2 = -0.5f * LOG2E_F / (l * l);
    const float* xr = x + (size_t)m * D;
    unsigned short hi[KP], lo[KP];
    float ssq = 0.f;
#pragma unroll
    for (int d = 0; d < D; ++d) {
        float v = xr[d];
        ssq = fmaf(v, v, ssq);
        unsigned short h = f32_to_bf16_rne(v);
        hi[d] = h;
        lo[d] = f32_to_bf16_rne(v - bf16_to_f32(h));
    }
#pragma unroll
    for (int d = D; d < KP; ++d) { hi[d] = 0; lo[d] = 0; }
#pragma unroll
    for (int q = 0; q < KP / 8; ++q) {
        bf16x8 vh, vl;
#pragma unroll
        for (int j = 0; j < 8; ++j) { vh[j] = (short)hi[q * 8 + j]; vl[j] = (short)lo[q * 8 + j]; }
        *reinterpret_cast<bf16x8*>(xhi + (size_t)m * KP + q * 8) = vh;
        *reinterpret_cast<bf16x8*>(xlo + (size_t)m * KP + q * 8) = vl;
    }
    cx[m] = c2 * ssq;
}

// ---- setup: samples -> (s_hi, s_lo bf16 [N][32]), w'[n] = sg^2 w_n 2^{c2||s||^2}
__global__ void prep_s(const float* __restrict__ s, const float* __restrict__ weights,
                       const float* __restrict__ sigma_p, const float* __restrict__ length_p,
                       unsigned short* __restrict__ shi, unsigned short* __restrict__ slo,
                       float* __restrict__ wp, int N) {
    int n = blockIdx.x * blockDim.x + threadIdx.x;
    if (n >= N) return;
    float l  = length_p[0];
    float sg = sigma_p[0];
    float c2 = -0.5f * LOG2E_F / (l * l);
    const float* sr = s + (size_t)n * D;
    unsigned short hi[KP], lo[KP];
    float ssq = 0.f;
#pragma unroll
    for (int d = 0; d < D; ++d) {
        float v = sr[d];
        ssq = fmaf(v, v, ssq);
        unsigned short h = f32_to_bf16_rne(v);
        hi[d] = h;
        lo[d] = f32_to_bf16_rne(v - bf16_to_f32(h));
    }
#pragma unroll
    for (int d = D; d < KP; ++d) { hi[d] = 0; lo[d] = 0; }
#pragma unroll
    for (int q = 0; q < KP / 8; ++q) {
        bf16x8 vh, vl;
#pragma unroll
        for (int j = 0; j < 8; ++j) { vh[j] = (short)hi[q * 8 + j]; vl[j] = (short)lo[q * 8 + j]; }
        *reinterpret_cast<bf16x8*>(shi + (size_t)n * KP + q * 8) = vh;
        *reinterpret_cast<bf16x8*>(slo + (size_t)n * KP + q * 8) = vl;
    }
    wp[n] = sg * sg * weights[n] * __builtin_amdgcn_exp2f(c2 * ssq);
}

// ---- main: each wave owns 2 column-tiles (32 m) x one n-chunk
__global__ __launch_bounds__(TPB) void ke_mfma(
    const unsigned short* __restrict__ xhi, const unsigned short* __restrict__ xlo,
    const unsigned short* __restrict__ shi, const unsigned short* __restrict__ slo,
    const float* __restrict__ wp, const float* __restrict__ cx,
    const float* __restrict__ length_p,
    float* __restrict__ out, int M, int N) {
    int lane = threadIdx.x & 63;
    int wave = blockIdx.x * (TPB / 64) + (threadIdx.x >> 6);
    int MG   = M / 32;                 // column-groups of 32
    int ns   = wave / MG;              // n-chunk id (block's 4 waves share ns)
    int mg   = wave - ns * MG;
    int m0   = mg * 32;
    int r    = lane & 15;
    int q    = lane >> 4;

    float l     = length_p[0];
    float m2c2  = LOG2E_F / (l * l);   // -2*c2  (log2 units)

    // B fragments (x) for both column-tiles, pinned for the whole n-loop.
    size_t xo0 = ((size_t)(m0 + r)) * KP + q * 8;
    size_t xo1 = ((size_t)(m0 + 16 + r)) * KP + q * 8;
    bf16x8 b0h = *reinterpret_cast<const bf16x8*>(xhi + xo0);
    bf16x8 b0l = *reinterpret_cast<const bf16x8*>(xlo + xo0);
    bf16x8 b1h = *reinterpret_cast<const bf16x8*>(xhi + xo1);
    bf16x8 b1l = *reinterpret_cast<const bf16x8*>(xlo + xo1);
    asm("" : "+v"(b0h), "+v"(b0l), "+v"(b1h), "+v"(b1l));

    int ntiles = N / 16;
    int per    = ntiles / NSPLIT;
    int t0     = ns * per;

    float p0 = 0.f, p1 = 0.f;
    for (int t = t0; t < t0 + per; ++t) {
        int n0 = t * 16;
        size_t so = ((size_t)(n0 + r)) * KP + q * 8;
        bf16x8 ah = *reinterpret_cast<const bf16x8*>(shi + so);
        bf16x8 al = *reinterpret_cast<const bf16x8*>(slo + so);
        f32x4 wq = *reinterpret_cast<const f32x4*>(wp + n0 + q * 4);

        f32x4 acc0 = {0.f, 0.f, 0.f, 0.f};
        f32x4 acc1 = {0.f, 0.f, 0.f, 0.f};
        acc0 = __builtin_amdgcn_mfma_f32_16x16x32_bf16(ah, b0h, acc0, 0, 0, 0);
        acc0 = __builtin_amdgcn_mfma_f32_16x16x32_bf16(ah, b0l, acc0, 0, 0, 0);
        acc0 = __builtin_amdgcn_mfma_f32_16x16x32_bf16(al, b0h, acc0, 0, 0, 0);
        acc1 = __builtin_amdgcn_mfma_f32_16x16x32_bf16(ah, b1h, acc1, 0, 0, 0);
        acc1 = __builtin_amdgcn_mfma_f32_16x16x32_bf16(ah, b1l, acc1, 0, 0, 0);
        acc1 = __builtin_amdgcn_mfma_f32_16x16x32_bf16(al, b1h, acc1, 0, 0, 0);
#pragma unroll
        for (int i = 0; i < 4; ++i) {
            p0 = fmaf(wq[i], __builtin_amdgcn_exp2f(m2c2 * acc0[i]), p0);
            p1 = fmaf(wq[i], __builtin_amdgcn_exp2f(m2c2 * acc1[i]), p1);
        }
    }
    // reduce the 4 lane-quarters (same column r, rows split over quarters)
    p0 += __shfl_xor(p0, 16, 64);
    p0 += __shfl_xor(p0, 32, 64);
    p1 += __shfl_xor(p1, 16, 64);
    p1 += __shfl_xor(p1, 32, 64);
    if (lane < 16) {
        atomicAdd(&out[m0 + r],      p0 * __builtin_amdgcn_exp2f(cx[m0 + r]));
        atomicAdd(&out[m0 + 16 + r], p1 * __builtin_amdgcn_exp2f(cx[m0 + 16 + r]));
    }
}

// ---- fallback: round-3 fp32 VALU kernel (no workspace needed)
typedef float v2f_ __attribute__((ext_vector_type(2)));
constexpr int MPT  = 2;
constexpr int MBLK = TPB * MPT;

__global__ __launch_bounds__(TPB) void ke_plain(
    const float* __restrict__ x, const float* __restrict__ samples,
    const float* __restrict__ weights, const float* __restrict__ sigma_p,
    const float* __restrict__ length_p, float* __restrict__ out,
    int M, int N, int nsplit, int chunk) {
    int mb = blockIdx.x / nsplit;
    int ns = blockIdx.x - mb * nsplit;
    int t  = threadIdx.x;
    int m0 = mb * MBLK + t;
    int m1 = m0 + TPB;
    int m0c = (m0 < M) ? m0 : 0;
    int m1c = (m1 < M) ? m1 : 0;

    v2f_ xaq[D / 2], xbq[D / 2];
    const v2f_* xp0 = reinterpret_cast<const v2f_*>(x + (size_t)m0c * D);
    const v2f_* xp1 = reinterpret_cast<const v2f_*>(x + (size_t)m1c * D);
#pragma unroll
    for (int qq = 0; qq < D / 2; ++qq) { xaq[qq] = xp0[qq]; xbq[qq] = xp1[qq]; }
#pragma unroll
    for (int qq = 0; qq < D / 2; ++qq) { asm("" : "+v"(xaq[qq])); asm("" : "+v"(xbq[qq])); }

    float l   = length_p[0];
    float c   = -0.5f * LOG2E_F / (l * l);
    float m2c = -2.f * c;
    float sg  = sigma_p[0];
    float sg2 = sg * sg;

    v2f_ qa = {0.f, 0.f}, qb = {0.f, 0.f};
#pragma unroll
    for (int qq = 0; qq < D / 2; ++qq) {
        qa = __builtin_elementwise_fma(xaq[qq], xaq[qq], qa);
        qb = __builtin_elementwise_fma(xbq[qq], xbq[qq], qb);
    }
    float cxa = c * (qa.x + qa.y);
    float cxb = c * (qb.x + qb.y);

    float acc0 = 0.f, acc1 = 0.f;
    int n0 = ns * chunk;
    int n1 = n0 + chunk;
    if (n1 > N) n1 = N;
#pragma unroll 2
    for (int n = n0; n < n1; ++n) {
        const v2f_* s2 = reinterpret_cast<const v2f_*>(samples + (size_t)n * D);
        v2f_ da = {0.f, 0.f}, db = {0.f, 0.f}, sq = {0.f, 0.f};
#pragma unroll
        for (int qq = 0; qq < D / 2; ++qq) {
            v2f_ sv = s2[qq];
            sq = __builtin_elementwise_fma(sv, sv, sq);
            da = __builtin_elementwise_fma(sv, xaq[qq], da);
            db = __builtin_elementwise_fma(sv, xbq[qq], db);
        }
        float cn = c * (sq.x + sq.y);
        float wn = sg2 * weights[n];
        float e0 = fmaf(m2c, da.x + da.y, cn);
        float e1 = fmaf(m2c, db.x + db.y, cn);
        acc0 = fmaf(wn, __builtin_amdgcn_exp2f(e0), acc0);
        acc1 = fmaf(wn, __builtin_amdgcn_exp2f(e1), acc1);
    }
    if (m0 < M) atomicAdd(&out[m0], acc0 * __builtin_amdgcn_exp2f(cxa));
    if (m1 < M) atomicAdd(&out[m1], acc1 * __builtin_amdgcn_exp2f(cxb));
}

extern "C" void kernel_launch(void* const* d_in, const int* in_sizes, int n_in,
                              void* d_out, int out_size, void* d_ws, size_t ws_size,
                              hipStream_t stream) {
    const float* x       = (const float*)d_in[0];
    const float* samples = (const float*)d_in[1];
    const float* weights = (const float*)d_in[2];
    const float* sigma_p = (const float*)d_in[3];
    const float* length_p= (const float*)d_in[4];
    float* out = (float*)d_out;

    int M = in_sizes[0] / D;
    int N = in_sizes[1] / D;

    hipMemsetAsync(out, 0, (size_t)out_size * sizeof(float), stream);

    // workspace layout (bytes)
    size_t xhi_off = 0;
    size_t xlo_off = xhi_off + (size_t)M * KP * 2;
    size_t shi_off = xlo_off + (size_t)M * KP * 2;
    size_t slo_off = shi_off + (size_t)N * KP * 2;
    size_t wp_off  = slo_off + (size_t)N * KP * 2;
    size_t cx_off  = wp_off + (size_t)N * 4;
    size_t need    = cx_off + (size_t)M * 4;

    bool mfma_ok = ws_size >= need && (M % 32) == 0 && (N % 16) == 0 &&
                   ((N / 16) % NSPLIT) == 0 && (((M / 32) * NSPLIT) % (TPB / 64)) == 0;

    if (mfma_ok) {
        char* ws = (char*)d_ws;
        unsigned short* xhi = (unsigned short*)(ws + xhi_off);
        unsigned short* xlo = (unsigned short*)(ws + xlo_off);
        unsigned short* shi = (unsigned short*)(ws + shi_off);
        unsigned short* slo = (unsigned short*)(ws + slo_off);
        float* wp = (float*)(ws + wp_off);
        float* cx = (float*)(ws + cx_off);

        prep_x<<<dim3((M + TPB - 1) / TPB), dim3(TPB), 0, stream>>>(
            x, length_p, xhi, xlo, cx, M);
        prep_s<<<dim3((N + TPB - 1) / TPB), dim3(TPB), 0, stream>>>(
            samples, weights, sigma_p, length_p, shi, slo, wp, N);

        int waves  = (M / 32) * NSPLIT;           // 8192
        int blocks = waves / (TPB / 64);          // 2048
        ke_mfma<<<dim3(blocks), dim3(TPB), 0, stream>>>(
            xhi, xlo, shi, slo, wp, cx, length_p, out, M, N);
    } else {
        int mbcnt  = (M + MBLK - 1) / MBLK;
        int nsplit = 2048 / (mbcnt > 0 ? mbcnt : 1);
        if (nsplit < 1) nsplit = 1;
        if (nsplit > N) nsplit = N;
        int chunk = (N + nsplit - 1) / nsplit;
        ke_plain<<<dim3(mbcnt * nsplit), dim3(TPB), 0, stream>>>(
            x, samples, weights, sigma_p, length_p, out, M, N, nsplit, chunk);
    }
}